// Round 24
// baseline (186.694 us; speedup 1.0000x reference)
//
#include <hip/hip_runtime.h>
#include <hip/hip_bf16.h>

// Problem constants (fixed by setup_inputs)
constexpr int B    = 4;
constexpr int CIN  = 512;
constexpr int NN   = 4096;
constexpr int CI   = 128;   // inter_channels
constexpr int CQ   = 32;    // PAM q/k dim
constexpr int COUT = 256;
constexpr int NSPLIT = 8;              // KV splits for pam flash
constexpr int KVLEN  = NN / NSPLIT;    // 512 KV cols per split
constexpr int ESPLIT = 32;             // K splits for cam energy

typedef __bf16 bf16x8 __attribute__((ext_vector_type(8)));
typedef __bf16 bf16x4 __attribute__((ext_vector_type(4)));
typedef float  f32x4  __attribute__((ext_vector_type(4)));

struct Ptr8 { float* p[8]; };

// ---------------------------------------------------------------------------
// Conv staging helpers (R21 geometry: 64n x 64co, BK=64):
//  - STAGE_X64:  fp32 X -> X^T tile [64n][64k] bf16, chunk-XOR swizzle.
//  - STAGE_X64B: bf16 X -> same tile (vector loads, no converts).
//  - CONV_MMA_STEP: 8 MFMAs per barrier pair (2 k-steps x 4 co-frags).
// ---------------------------------------------------------------------------
#define STAGE_X64(Xb_, kb_)                                                   \
    {                                                                         \
        const int k_   = t >> 2;          /* 0..63 */                         \
        const int n16_ = (t & 3) * 16;                                        \
        const float* src_ = (Xb_) + (size_t)((kb_) + k_) * N + n0 + n16_;     \
        _Pragma("unroll")                                                     \
        for (int jj_ = 0; jj_ < 4; ++jj_) {                                   \
            float4 f_ = *reinterpret_cast<const float4*>(src_ + 4 * jj_);     \
            float fv_[4] = {f_.x, f_.y, f_.z, f_.w};                          \
            _Pragma("unroll")                                                 \
            for (int e_ = 0; e_ < 4; ++e_) {                                  \
                int n_ = n16_ + 4 * jj_ + e_;                                 \
                int ks_ = k_ ^ ((((n_) >> 3) & 3) << 3);                      \
                Xs[n_][ks_] = (__bf16)fv_[e_];                                \
            }                                                                 \
        }                                                                     \
    }

#define STAGE_X64B(Xb_, kb_)                                                  \
    {                                                                         \
        const int k_   = t >> 2;          /* 0..63 */                         \
        const int n16_ = (t & 3) * 16;                                        \
        const __bf16* src_ = (Xb_) + (size_t)((kb_) + k_) * N + n0 + n16_;    \
        bf16x8 a0_ = *reinterpret_cast<const bf16x8*>(src_);                  \
        bf16x8 a1_ = *reinterpret_cast<const bf16x8*>(src_ + 8);              \
        _Pragma("unroll")                                                     \
        for (int e_ = 0; e_ < 8; ++e_) {                                      \
            int n_ = n16_ + e_;                                               \
            Xs[n_][k_ ^ ((((n_) >> 3) & 3) << 3)] = a0_[e_];                  \
        }                                                                     \
        _Pragma("unroll")                                                     \
        for (int e_ = 0; e_ < 8; ++e_) {                                      \
            int n_ = n16_ + 8 + e_;                                           \
            Xs[n_][k_ ^ ((((n_) >> 3) & 3) << 3)] = a1_[e_];                  \
        }                                                                     \
    }

#define CONV_MMA_STEP()                                                       \
    {                                                                         \
        const int row_ = 16 * w + c;                                          \
        const int xsw_ = (((row_ >> 3) & 3) << 3);                            \
        _Pragma("unroll")                                                     \
        for (int ks2_ = 0; ks2_ < 2; ++ks2_) {                                \
            bf16x8 xa_ = *reinterpret_cast<const bf16x8*>(                    \
                &Xs[row_][(ks2_ * 32 + g * 8) ^ xsw_]);                       \
            _Pragma("unroll")                                                 \
            for (int cb_ = 0; cb_ < 4; ++cb_) {                               \
                bf16x8 wf_ = *reinterpret_cast<const bf16x8*>(                \
                    &Ws[16 * cb_ + c][ks2_ * 32 + g * 8]);                    \
                acc[cb_] = __builtin_amdgcn_mfma_f32_16x16x32_bf16(           \
                    xa_, wf_, acc[cb_], 0, 0, 0);                             \
            }                                                                 \
        }                                                                     \
    }

#define STAGE_W64(srcp_)                                                      \
    {                                                                         \
        bf16x8 u0, u1;                                                        \
        _Pragma("unroll")                                                     \
        for (int jj = 0; jj < 2; ++jj) {                                      \
            float4 f0 = *reinterpret_cast<const float4*>((srcp_) + 8 * jj);   \
            float4 f1 = *reinterpret_cast<const float4*>((srcp_) + 8 * jj + 4);\
            bf16x8& u = jj ? u1 : u0;                                         \
            u[0]=(__bf16)f0.x; u[1]=(__bf16)f0.y; u[2]=(__bf16)f0.z; u[3]=(__bf16)f0.w;\
            u[4]=(__bf16)f1.x; u[5]=(__bf16)f1.y; u[6]=(__bf16)f1.z; u[7]=(__bf16)f1.w;\
        }                                                                     \
        *reinterpret_cast<bf16x8*>(&Ws[t >> 2][kh])     = u0;                 \
        *reinterpret_cast<bf16x8*>(&Ws[t >> 2][kh + 8]) = u1;                 \
    }

// ---------------------------------------------------------------------------
// General MFMA 1x1-conv, 64n x 64co, BK=64. XBF16 selects bf16 X input.
// ---------------------------------------------------------------------------
template<bool RELU, bool XBF16>
__global__ __launch_bounds__(256) void conv_mfma(
    const float* __restrict__ W, long wbs,
    const void* __restrict__ Xv, long xbs,
    float* __restrict__ Y,
    const float* __restrict__ bias,
    const float* __restrict__ gamma_ptr,
    const float* __restrict__ resid, long rbs,
    int Co, int K, int N)
{
    const int b   = blockIdx.z;
    const int n0  = blockIdx.x * 64;
    const int co0 = blockIdx.y * 64;
    const float* Wb = W + (size_t)b * wbs;

    __shared__ __bf16 Xs[64][72];
    __shared__ __bf16 Ws[64][72];

    const int t    = threadIdx.x;
    const int w    = t >> 6;
    const int lane = t & 63;
    const int g    = lane >> 4;
    const int c    = lane & 15;

    f32x4 acc[4];
    #pragma unroll
    for (int cb = 0; cb < 4; ++cb) acc[cb] = (f32x4){0.f, 0.f, 0.f, 0.f};

    for (int kb = 0; kb < K; kb += 64) {
        if constexpr (XBF16) {
            STAGE_X64B(((const __bf16*)Xv + (size_t)b * xbs), kb)
        } else {
            STAGE_X64(((const float*)Xv + (size_t)b * xbs), kb)
        }
        {
            const int kh = (t & 3) * 16;
            const float* src = Wb + (size_t)(co0 + (t >> 2)) * K + kb + kh;
            STAGE_W64(src)
        }
        __syncthreads();
        CONV_MMA_STEP()
        __syncthreads();
    }

    const float gsc = gamma_ptr ? *gamma_ptr : 1.f;
    const int nb = n0 + 16 * w + 4 * g;
    #pragma unroll
    for (int cb = 0; cb < 4; ++cb) {
        int co = co0 + 16 * cb + c;
        float bv = bias ? bias[co] : 0.f;
        float4 o;
        float* op = &o.x;
        #pragma unroll
        for (int r = 0; r < 4; ++r) {
            float val = acc[cb][r] + bv;
            if (RELU) val = fmaxf(val, 0.f);
            val *= gsc;
            op[r] = val;
        }
        if (resid) {
            size_t roff = (size_t)b * rbs + (size_t)co * N + nb;
            float4 rv = *reinterpret_cast<const float4*>(&resid[roff]);
            o.x += rv.x; o.y += rv.y; o.z += rv.z; o.w += rv.w;
        }
        *reinterpret_cast<float4*>(&Y[(size_t)b * Co * N + (size_t)co * N + nb]) = o;
    }
}

// ---------------------------------------------------------------------------
// Dual conv (fp32 X): rows [0,128) = relu(Wlo@Xlo), [128,256) = relu(Whi@Xhi).
// OUTBF16 selects bf16 output. Grid (N/64, 4, B).
// ---------------------------------------------------------------------------
template<bool RELU, bool OUTBF16>
__global__ __launch_bounds__(256) void conv_dual(
    const float* __restrict__ Wlo, const float* __restrict__ Whi, int K,
    const float* __restrict__ Xlo, long xbslo,
    const float* __restrict__ Xhi, long xbshi,
    void* __restrict__ Y, long ybs, int N)
{
    const int b   = blockIdx.z;
    const int n0  = blockIdx.x * 64;
    const int co0 = blockIdx.y * 64;
    const bool lo = (co0 < 128);
    const float* Wb = lo ? (Wlo + (size_t)co0 * K) : (Whi + (size_t)(co0 - 128) * K);
    const float* Xb = lo ? (Xlo + (size_t)b * xbslo) : (Xhi + (size_t)b * xbshi);

    __shared__ __bf16 Xs[64][72];
    __shared__ __bf16 Ws[64][72];

    const int t    = threadIdx.x;
    const int w    = t >> 6;
    const int lane = t & 63;
    const int g    = lane >> 4;
    const int c    = lane & 15;

    f32x4 acc[4];
    #pragma unroll
    for (int cb = 0; cb < 4; ++cb) acc[cb] = (f32x4){0.f, 0.f, 0.f, 0.f};

    for (int kb = 0; kb < K; kb += 64) {
        STAGE_X64(Xb, kb)
        {
            const int kh = (t & 3) * 16;
            const float* src = Wb + (size_t)(t >> 2) * K + kb + kh;
            STAGE_W64(src)
        }
        __syncthreads();
        CONV_MMA_STEP()
        __syncthreads();
    }

    const int nb = n0 + 16 * w + 4 * g;
    #pragma unroll
    for (int cb = 0; cb < 4; ++cb) {
        int co = co0 + 16 * cb + c;
        if constexpr (OUTBF16) {
            bf16x4 o;
            #pragma unroll
            for (int r = 0; r < 4; ++r) {
                float val = acc[cb][r];
                if (RELU) val = fmaxf(val, 0.f);
                o[r] = (__bf16)val;
            }
            *reinterpret_cast<bf16x4*>(
                &((__bf16*)Y)[(size_t)b * ybs + (size_t)co * N + nb]) = o;
        } else {
            float4 o;
            float* op = &o.x;
            #pragma unroll
            for (int r = 0; r < 4; ++r) {
                float val = acc[cb][r];
                if (RELU) val = fmaxf(val, 0.f);
                op[r] = val;
            }
            *reinterpret_cast<float4*>(
                &((float*)Y)[(size_t)b * ybs + (size_t)co * N + nb]) = o;
        }
    }
}

// ---------------------------------------------------------------------------
// Concat-K conv, bf16 in / bf16 out: T = W1@X[0:128] + W2@X[128:256] + b1+b2.
// ---------------------------------------------------------------------------
__global__ __launch_bounds__(256) void conv_catk(
    const float* __restrict__ W1, const float* __restrict__ W2,
    const float* __restrict__ b1, const float* __restrict__ b2,
    const __bf16* __restrict__ X, long xbs,
    __bf16* __restrict__ Y, int N)
{
    const int b   = blockIdx.z;
    const int n0  = blockIdx.x * 64;
    const int co0 = blockIdx.y * 64;
    const __bf16* Xb = X + (size_t)b * xbs;

    __shared__ __bf16 Xs[64][72];
    __shared__ __bf16 Ws[64][72];

    const int t    = threadIdx.x;
    const int w    = t >> 6;
    const int lane = t & 63;
    const int g    = lane >> 4;
    const int c    = lane & 15;

    f32x4 acc[4];
    #pragma unroll
    for (int cb = 0; cb < 4; ++cb) acc[cb] = (f32x4){0.f, 0.f, 0.f, 0.f};

    for (int kb = 0; kb < 256; kb += 64) {
        STAGE_X64B(Xb, kb)
        {
            const int kh = (t & 3) * 16;
            const int kcol = kb + kh;
            const float* src = (kb < 128)
                ? (W1 + (size_t)(co0 + (t >> 2)) * 128 + kcol)
                : (W2 + (size_t)(co0 + (t >> 2)) * 128 + kcol - 128);
            STAGE_W64(src)
        }
        __syncthreads();
        CONV_MMA_STEP()
        __syncthreads();
    }

    const int nb = n0 + 16 * w + 4 * g;
    #pragma unroll
    for (int cb = 0; cb < 4; ++cb) {
        int co = co0 + 16 * cb + c;
        float bv = b1[co] + b2[co];
        bf16x4 o;
        #pragma unroll
        for (int r = 0; r < 4; ++r) o[r] = (__bf16)(acc[cb][r] + bv);
        *reinterpret_cast<bf16x4*>(&Y[(size_t)b * 256 * N + (size_t)co * N + nb]) = o;
    }
}

// ---------------------------------------------------------------------------
// Fused q/k/v conv from f1 (= F rows 0-127, batch stride 256N). 64-co, BK=64.
// ---------------------------------------------------------------------------
__global__ __launch_bounds__(256) void conv_qkv(
    const float* __restrict__ Wq, const float* __restrict__ bq,
    const float* __restrict__ Wk, const float* __restrict__ bk,
    const float* __restrict__ Wv, const float* __restrict__ bv,
    const float* __restrict__ F, __bf16* __restrict__ qkT,
    __bf16* __restrict__ Vbuf, int N)
{
    const int b   = blockIdx.z;
    const int n0  = blockIdx.x * 64;
    const int co0 = blockIdx.y * 64;
    const float* Xb = F + (size_t)b * 256 * N;   // f1 rows 0-127

    __shared__ __bf16 Xs[64][72];
    __shared__ __bf16 Ws[64][72];

    const int t    = threadIdx.x;
    const int w    = t >> 6;
    const int lane = t & 63;
    const int g    = lane >> 4;
    const int c    = lane & 15;

    f32x4 acc[4];
    #pragma unroll
    for (int cb = 0; cb < 4; ++cb) acc[cb] = (f32x4){0.f, 0.f, 0.f, 0.f};

    for (int kb = 0; kb < CI; kb += 64) {
        STAGE_X64(Xb, kb)
        {
            const int co = co0 + (t >> 2);
            const int kh = (t & 3) * 16;
            const float* src = (co < 32) ? (Wq + (size_t)co * CI)
                             : (co < 64) ? (Wk + (size_t)(co - 32) * CI)
                                         : (Wv + (size_t)(co - 64) * CI);
            src += kb + kh;
            STAGE_W64(src)
        }
        __syncthreads();
        CONV_MMA_STEP()
        __syncthreads();
    }

    const int nb = n0 + 16 * w + 4 * g;
    #pragma unroll
    for (int cb = 0; cb < 4; ++cb) {
        int co = co0 + 16 * cb + c;
        float bias = (co < 32) ? bq[co] : (co < 64) ? bk[co - 32] : bv[co - 64];
        if (co < 64) {
            #pragma unroll
            for (int r = 0; r < 4; ++r)
                qkT[((size_t)b * NN + nb + r) * 64 + co] = (__bf16)(acc[cb][r] + bias);
        } else {
            bf16x4 o;
            #pragma unroll
            for (int r = 0; r < 4; ++r) o[r] = (__bf16)(acc[cb][r] + bias);
            *reinterpret_cast<bf16x4*>(&Vbuf[((size_t)b * CI + co - 64) * NN + nb]) = o;
        }
    }
}

// ---------------------------------------------------------------------------
// PAM flash, NSPLIT=8 (KVLEN=512): same inner loop as R21-R23; grid.z=8 for
// occupancy (2048 blocks = 8/CU launch, LDS caps at 6/CU = 75% wave ceiling).
// ---------------------------------------------------------------------------
__global__ __launch_bounds__(256) void pam_flash_mfma(
    const __bf16* __restrict__ qkT, const __bf16* __restrict__ Vbuf,
    Ptr8 op8,
    float* __restrict__ mp, float* __restrict__ lp, int N)
{
    const int b  = blockIdx.y;
    const int s  = blockIdx.z;
    const int n0 = blockIdx.x * 64;
    float* Op = op8.p[s];

    __shared__ __bf16 Vlds[2][128][40];
    __shared__ __bf16 QP[64][40];

    const int t    = threadIdx.x;
    const int w    = t >> 6;
    const int lane = t & 63;
    const int g    = lane >> 4;
    const int c    = lane & 15;

    bf16x8 qa = *reinterpret_cast<const bf16x8*>(
        &qkT[((size_t)b * NN + n0 + 16*w + c) * 64 + g * 8]);

    f32x4 acc[8];
    #pragma unroll
    for (int vbk = 0; vbk < 8; ++vbk) acc[vbk] = (f32x4){0.f, 0.f, 0.f, 0.f};
    float ms = -1e30f, ls = 0.f;

    const int mstart = s * KVLEN;
    const int NT = KVLEN / 32;

    auto stageV = [&](int mt, int buf) {
        const int cv  = t >> 1;
        const int sw  = (cv >> 3) & 3;
        const int ch0 = (t & 1) * 2;
        const __bf16* src = &Vbuf[((size_t)b * CI + cv) * NN + mstart + mt * 32 + ch0 * 8];
        *reinterpret_cast<bf16x8*>(&Vlds[buf][cv][((ch0 ^ sw) & 3) * 8]) =
            *reinterpret_cast<const bf16x8*>(src);
        *reinterpret_cast<bf16x8*>(&Vlds[buf][cv][(((ch0 + 1) ^ sw) & 3) * 8]) =
            *reinterpret_cast<const bf16x8*>(src + 8);
    };

    stageV(0, 0);
    __syncthreads();

    for (int mt = 0; mt < NT; ++mt) {
        const int buf = mt & 1;
        const int m0  = mstart + mt * 32;
        if (mt + 1 < NT) stageV(mt + 1, buf ^ 1);

        f32x4 sv[2];
        #pragma unroll
        for (int mb = 0; mb < 2; ++mb) {
            bf16x8 kf = *reinterpret_cast<const bf16x8*>(
                &qkT[((size_t)b * NN + m0 + 16*mb + c) * 64 + 32 + g * 8]);
            sv[mb] = __builtin_amdgcn_mfma_f32_16x16x32_bf16(
                kf, qa, (f32x4){0.f, 0.f, 0.f, 0.f}, 0, 0, 0);
        }

        float mx = sv[0][0];
        #pragma unroll
        for (int r = 1; r < 4; ++r) mx = fmaxf(mx, sv[0][r]);
        #pragma unroll
        for (int r = 0; r < 4; ++r) mx = fmaxf(mx, sv[1][r]);
        mx = fmaxf(mx, __shfl_xor(mx, 16));
        mx = fmaxf(mx, __shfl_xor(mx, 32));
        float mnew = fmaxf(ms, mx);
        float scale = __expf(ms - mnew);
        ms = mnew;
        float psum = 0.f;
        #pragma unroll
        for (int mb = 0; mb < 2; ++mb)
            #pragma unroll
            for (int r = 0; r < 4; ++r) {
                float p = __expf(sv[mb][r] - mnew);
                sv[mb][r] = p;
                psum += p;
            }
        psum += __shfl_xor(psum, 16);
        psum += __shfl_xor(psum, 32);
        ls = ls * scale + psum;

        #pragma unroll
        for (int mb = 0; mb < 2; ++mb) {
            bf16x4 pk;
            #pragma unroll
            for (int r = 0; r < 4; ++r) pk[r] = (__bf16)sv[mb][r];
            *reinterpret_cast<bf16x4*>(&QP[16*w + c][16*mb + 4*g]) = pk;
        }

        if (__any(scale != 1.0f)) {
            float sc[4];
            #pragma unroll
            for (int r = 0; r < 4; ++r) sc[r] = __shfl(scale, 4*g + r, 64);
            #pragma unroll
            for (int vbk = 0; vbk < 8; ++vbk)
                #pragma unroll
                for (int r = 0; r < 4; ++r) acc[vbk][r] *= sc[r];
        }

        bf16x8 pa = *reinterpret_cast<const bf16x8*>(&QP[16*w + c][g * 8]);
        #pragma unroll
        for (int vbk = 0; vbk < 8; ++vbk) {
            const int row = 16*vbk + c;
            const int sw  = (2*vbk + (c >> 3)) & 3;
            bf16x8 vf = *reinterpret_cast<const bf16x8*>(
                &Vlds[buf][row][((g ^ sw) & 3) * 8]);
            acc[vbk] = __builtin_amdgcn_mfma_f32_16x16x32_bf16(pa, vf, acc[vbk], 0, 0, 0);
        }
        __syncthreads();
    }

    #pragma unroll
    for (int vbk = 0; vbk < 8; ++vbk) {
        float4 o = { acc[vbk][0], acc[vbk][1], acc[vbk][2], acc[vbk][3] };
        *reinterpret_cast<float4*>(
            &Op[((size_t)(b * CI + 16*vbk + c)) * N + n0 + 16*w + 4*g]) = o;
    }
    if (g == 0) {
        int n = n0 + 16*w + c;
        mp[(size_t)(s * B + b) * N + n] = ms;
        lp[(size_t)(s * B + b) * N + n] = ls;
    }
}

// ---------------------------------------------------------------------------
// Merge NSPLIT=8 partials; writes sa IN-PLACE into f1 (F rows 0-127).
// ---------------------------------------------------------------------------
__global__ __launch_bounds__(256) void pam_merge(
    Ptr8 op8,
    const float* __restrict__ mp, const float* __restrict__ lp,
    float* __restrict__ F, const float* __restrict__ gamma_ptr)
{
    size_t idx = (size_t)blockIdx.x * 256 + threadIdx.x;
    const int n = (int)(idx & (NN - 1));
    const int b = (int)(idx >> 19);

    float m[NSPLIT], l[NSPLIT];
    float M = -1e30f;
    #pragma unroll
    for (int s = 0; s < NSPLIT; ++s) {
        m[s] = mp[(size_t)(s * B + b) * NN + n];
        l[s] = lp[(size_t)(s * B + b) * NN + n];
        M = fmaxf(M, m[s]);
    }
    float L = 0.f, O = 0.f;
    #pragma unroll
    for (int s = 0; s < NSPLIT; ++s) {
        float ws = __expf(m[s] - M);
        L += l[s] * ws;
        O += op8.p[s][idx] * ws;
    }
    size_t foff = (size_t)b * (256 * (size_t)NN) + (idx & ((1u << 19) - 1));
    F[foff] = (*gamma_ptr) * (O / L) + F[foff];
}

// ---------------------------------------------------------------------------
// CAM energy, K-split partials (strided f2 input).
// ---------------------------------------------------------------------------
__global__ __launch_bounds__(256) void cam_energy_part(
    const float* __restrict__ f2, long f2bs, float* __restrict__ ep, int N)
{
    const int b = blockIdx.x;
    const int s = blockIdx.y;
    const float* fb = f2 + (size_t)b * f2bs;
    const int kbase = s * (NN / ESPLIT);

    __shared__ float fs[128][33];
    const int t  = threadIdx.x;
    const int ti = t >> 4;
    const int tj = t & 15;

    float acc[8][8] = {};
    for (int st = 0; st < (NN / ESPLIT) / 32; ++st) {
        const int k0 = kbase + st * 32;
        {
            const int ch  = t >> 1;
            const int k16 = (t & 1) * 16;
            const float* src = fb + (size_t)ch * N + k0 + k16;
            #pragma unroll
            for (int j = 0; j < 4; ++j)
                *reinterpret_cast<float4*>(&fs[ch][k16 + 4*j]) =
                    *reinterpret_cast<const float4*>(src + 4*j);
        }
        __syncthreads();
        #pragma unroll 4
        for (int k = 0; k < 32; ++k) {
            float av[8], bv[8];
            #pragma unroll
            for (int ii = 0; ii < 8; ++ii) av[ii] = fs[ti * 8 + ii][k];
            #pragma unroll
            for (int jj = 0; jj < 8; ++jj) bv[jj] = fs[tj * 8 + jj][k];
            #pragma unroll
            for (int ii = 0; ii < 8; ++ii)
                #pragma unroll
                for (int jj = 0; jj < 8; ++jj)
                    acc[ii][jj] += av[ii] * bv[jj];
        }
        __syncthreads();
    }
    float* dst = ep + ((size_t)(s * B + b)) * CI * CI;
    #pragma unroll
    for (int ii = 0; ii < 8; ++ii)
        #pragma unroll
        for (int jj = 0; jj < 8; ++jj)
            dst[(size_t)(ti * 8 + ii) * CI + tj * 8 + jj] = acc[ii][jj];
}

__global__ __launch_bounds__(256) void cam_energy_reduce(
    const float* __restrict__ ep, float* __restrict__ came)
{
    const size_t n = (size_t)B * CI * CI;
    size_t idx = (size_t)blockIdx.x * 256 + threadIdx.x;
    float s = 0.f;
    #pragma unroll
    for (int j = 0; j < ESPLIT; ++j) s += ep[j * n + idx];
    came[idx] = s;
}

// ---------------------------------------------------------------------------
// CAM softmax: softmax(rowmax - e) == exp(rowmin - e)/sum.
// ---------------------------------------------------------------------------
__global__ __launch_bounds__(64) void cam_softmax(
    const float* __restrict__ e, float* __restrict__ attn)
{
    const int row = blockIdx.x;
    const float* er = e + (size_t)row * CI;
    const int t = threadIdx.x;
    float v0 = er[t], v1 = er[t + 64];
    float mn = fminf(v0, v1);
    #pragma unroll
    for (int off = 32; off; off >>= 1) mn = fminf(mn, __shfl_xor(mn, off));
    float p0 = __expf(mn - v0), p1 = __expf(mn - v1);
    float s = p0 + p1;
    #pragma unroll
    for (int off = 32; off; off >>= 1) s += __shfl_xor(s, off);
    float inv = 1.f / s;
    attn[(size_t)row * CI + t]      = p0 * inv;
    attn[(size_t)row * CI + t + 64] = p1 * inv;
}

// ---------------------------------------------------------------------------
extern "C" void kernel_launch(void* const* d_in, const int* in_sizes, int n_in,
                              void* d_out, int out_size, void* d_ws, size_t ws_size,
                              hipStream_t stream)
{
    const float* x    = (const float*)d_in[0];
    const float* Wa   = (const float*)d_in[1];
    const float* Wc   = (const float*)d_in[2];
    const float* Wq   = (const float*)d_in[3];
    const float* bq   = (const float*)d_in[4];
    const float* Wk   = (const float*)d_in[5];
    const float* bk   = (const float*)d_in[6];
    const float* Wv   = (const float*)d_in[7];
    const float* bv   = (const float*)d_in[8];
    const float* gpam = (const float*)d_in[9];
    const float* gcam = (const float*)d_in[10];
    const float* Wa1  = (const float*)d_in[11];
    const float* Wc1  = (const float*)d_in[12];
    const float* W1   = (const float*)d_in[13];
    const float* b1   = (const float*)d_in[14];
    const float* W2   = (const float*)d_in[15];
    const float* b2   = (const float*)d_in[16];
    const float* W3   = (const float*)d_in[17];
    const float* b3   = (const float*)d_in[18];
    float* out = (float*)d_out;

    // workspace layout (fp32 units) — ~72 MB (77 MB proven safe in R10)
    const size_t PART = (size_t)B * CI * NN;   // 2,097,152
    float* ws    = (float*)d_ws;
    float*  F     = ws;                          // [B,256,N] fp32 (f1|f2), 2*PART
    float*  R2    = ws + 2 * PART;               // PART: flash partial 5 -> epart -> S2 bf16
    float*  epart = R2;
    __bf16* S2bf  = (__bf16*)R2;
    float*  Csc   = ws + 3 * PART;               // PART: flash partial 3 -> sc fp32
    float*  Treg  = ws + 4 * PART;               // PART: flash partial 4 -> T bf16
    __bf16* Tbf   = (__bf16*)Treg;
    float*  Opart = ws + 5 * PART;               // 3*PART: flash partials 0-2
    float*  mpart = ws + 8 * PART;               // [8][B][N] 131,072
    float*  lpart = mpart + 131072;              // [8][B][N] 131,072
    float*  came  = lpart + 131072;
    float*  cama  = came + 65536;
    __bf16* qkT   = (__bf16*)(cama + 65536);         // [B][N][64] bf16
    __bf16* Vbuf  = (__bf16*)(cama + 65536 + 524288);// [B][128][N] bf16

    // 8 flash partials in dead-at-flash-time regions:
    Ptr8 op8;
    op8.p[0] = Opart;          op8.p[1] = Opart + PART;
    op8.p[2] = Opart + 2*PART; op8.p[3] = Csc;      // sc written later (step 6)
    op8.p[4] = Treg;           op8.p[5] = R2;       // epart/S2 written later
    op8.p[6] = out;            op8.p[7] = out + PART; // overwritten by W3

    const dim3 blk(256);

    // 1. F = relu([Wa;Wc] @ x), fp32 out
    conv_dual<true, false><<<dim3(NN / 64, 4, B), blk, 0, stream>>>(
        Wa, Wc, CIN, x, (long)CIN * NN, x, (long)CIN * NN, F, (long)256 * NN, NN);
    // 2. qkT + Vbuf from f1
    conv_qkv<<<dim3(NN / 64, 3, B), blk, 0, stream>>>(
        Wq, bq, Wk, bk, Wv, bv, F, qkT, Vbuf, NN);
    // 3. flash partials (NSPLIT=8)
    pam_flash_mfma<<<dim3(NN / 64, B, NSPLIT), blk, 0, stream>>>(
        qkT, Vbuf, op8, mpart, lpart, NN);
    // 4. merge -> sa in-place into F rows 0-127
    pam_merge<<<dim3((B * CI * NN) / 256), blk, 0, stream>>>(
        op8, mpart, lpart, F, gpam);
    // 5. CAM energy (f2 = F rows 128+), partials into epart
    cam_energy_part<<<dim3(B, ESPLIT), blk, 0, stream>>>(
        F + (size_t)128 * NN, (long)256 * NN, epart, NN);
    cam_energy_reduce<<<dim3((B * CI * CI) / 256), blk, 0, stream>>>(epart, came);
    cam_softmax<<<dim3(B * CI), dim3(64), 0, stream>>>(came, cama);
    // 6. sc = gamma_cam * (attn @ f2) + f2 -> Csc (fp32)
    conv_mfma<false, false><<<dim3(NN / 64, 2, B), blk, 0, stream>>>(
        cama, (long)CI * CI, F + (size_t)128 * NN, (long)256 * NN, Csc,
        nullptr, gcam, F + (size_t)128 * NN, (long)256 * NN, CI, CI, NN);
    // 7. S2 = [relu(Wa1@sa) ; relu(Wc1@sc)] -> bf16 (epart dead now)
    conv_dual<true, true><<<dim3(NN / 64, 4, B), blk, 0, stream>>>(
        Wa1, Wc1, CI, F, (long)256 * NN, Csc, (long)CI * NN, S2bf, (long)256 * NN, NN);
    // 8. T = [W1 W2] @ S2 + b1 + b2 -> bf16
    conv_catk<<<dim3(NN / 64, 4, B), blk, 0, stream>>>(
        W1, W2, b1, b2, S2bf, (long)256 * NN, Tbf, NN);
    // 9. out = W3 @ T + b3 (bf16 X)
    conv_mfma<false, true><<<dim3(NN / 64, 4, B), blk, 0, stream>>>(
        W3, 0, Tbf, (long)COUT * NN, out, b3, nullptr, nullptr, 0, COUT, COUT, NN);
}

// Round 25
// 177.228 us; speedup vs baseline: 1.0534x; 1.0534x over previous
//
#include <hip/hip_runtime.h>
#include <hip/hip_bf16.h>

// Problem constants (fixed by setup_inputs)
constexpr int B    = 4;
constexpr int CIN  = 512;
constexpr int NN   = 4096;
constexpr int CI   = 128;   // inter_channels
constexpr int CQ   = 32;    // PAM q/k dim
constexpr int COUT = 256;
constexpr int NSPLIT = 4;              // KV splits for pam flash
constexpr int KVLEN  = NN / NSPLIT;    // 1024 KV cols per split
constexpr int ESPLIT = 32;             // K splits for cam energy

typedef __bf16 bf16x8 __attribute__((ext_vector_type(8)));
typedef __bf16 bf16x4 __attribute__((ext_vector_type(4)));
typedef float  f32x4  __attribute__((ext_vector_type(4)));

struct Ptr4 { float* p[4]; };

// ---------------------------------------------------------------------------
// Conv staging helpers (R21 geometry: 64n x 64co, BK=64):
//  - STAGE_X64:  fp32 X -> X^T tile [64n][64k] bf16, chunk-XOR swizzle.
//  - STAGE_X64B: bf16 X -> same tile (vector loads, no converts).
//  - CONV_MMA_STEP: 8 MFMAs per barrier pair (2 k-steps x 4 co-frags).
// ---------------------------------------------------------------------------
#define STAGE_X64(Xb_, kb_)                                                   \
    {                                                                         \
        const int k_   = t >> 2;          /* 0..63 */                         \
        const int n16_ = (t & 3) * 16;                                        \
        const float* src_ = (Xb_) + (size_t)((kb_) + k_) * N + n0 + n16_;     \
        _Pragma("unroll")                                                     \
        for (int jj_ = 0; jj_ < 4; ++jj_) {                                   \
            float4 f_ = *reinterpret_cast<const float4*>(src_ + 4 * jj_);     \
            float fv_[4] = {f_.x, f_.y, f_.z, f_.w};                          \
            _Pragma("unroll")                                                 \
            for (int e_ = 0; e_ < 4; ++e_) {                                  \
                int n_ = n16_ + 4 * jj_ + e_;                                 \
                int ks_ = k_ ^ ((((n_) >> 3) & 3) << 3);                      \
                Xs[n_][ks_] = (__bf16)fv_[e_];                                \
            }                                                                 \
        }                                                                     \
    }

#define STAGE_X64B(Xb_, kb_)                                                  \
    {                                                                         \
        const int k_   = t >> 2;          /* 0..63 */                         \
        const int n16_ = (t & 3) * 16;                                        \
        const __bf16* src_ = (Xb_) + (size_t)((kb_) + k_) * N + n0 + n16_;    \
        bf16x8 a0_ = *reinterpret_cast<const bf16x8*>(src_);                  \
        bf16x8 a1_ = *reinterpret_cast<const bf16x8*>(src_ + 8);              \
        _Pragma("unroll")                                                     \
        for (int e_ = 0; e_ < 8; ++e_) {                                      \
            int n_ = n16_ + e_;                                               \
            Xs[n_][k_ ^ ((((n_) >> 3) & 3) << 3)] = a0_[e_];                  \
        }                                                                     \
        _Pragma("unroll")                                                     \
        for (int e_ = 0; e_ < 8; ++e_) {                                      \
            int n_ = n16_ + 8 + e_;                                           \
            Xs[n_][k_ ^ ((((n_) >> 3) & 3) << 3)] = a1_[e_];                  \
        }                                                                     \
    }

#define CONV_MMA_STEP()                                                       \
    {                                                                         \
        const int row_ = 16 * w + c;                                          \
        const int xsw_ = (((row_ >> 3) & 3) << 3);                            \
        _Pragma("unroll")                                                     \
        for (int ks2_ = 0; ks2_ < 2; ++ks2_) {                                \
            bf16x8 xa_ = *reinterpret_cast<const bf16x8*>(                    \
                &Xs[row_][(ks2_ * 32 + g * 8) ^ xsw_]);                       \
            _Pragma("unroll")                                                 \
            for (int cb_ = 0; cb_ < 4; ++cb_) {                               \
                bf16x8 wf_ = *reinterpret_cast<const bf16x8*>(                \
                    &Ws[16 * cb_ + c][ks2_ * 32 + g * 8]);                    \
                acc[cb_] = __builtin_amdgcn_mfma_f32_16x16x32_bf16(           \
                    xa_, wf_, acc[cb_], 0, 0, 0);                             \
            }                                                                 \
        }                                                                     \
    }

#define STAGE_W64(srcp_)                                                      \
    {                                                                         \
        bf16x8 u0, u1;                                                        \
        _Pragma("unroll")                                                     \
        for (int jj = 0; jj < 2; ++jj) {                                      \
            float4 f0 = *reinterpret_cast<const float4*>((srcp_) + 8 * jj);   \
            float4 f1 = *reinterpret_cast<const float4*>((srcp_) + 8 * jj + 4);\
            bf16x8& u = jj ? u1 : u0;                                         \
            u[0]=(__bf16)f0.x; u[1]=(__bf16)f0.y; u[2]=(__bf16)f0.z; u[3]=(__bf16)f0.w;\
            u[4]=(__bf16)f1.x; u[5]=(__bf16)f1.y; u[6]=(__bf16)f1.z; u[7]=(__bf16)f1.w;\
        }                                                                     \
        *reinterpret_cast<bf16x8*>(&Ws[t >> 2][kh])     = u0;                 \
        *reinterpret_cast<bf16x8*>(&Ws[t >> 2][kh + 8]) = u1;                 \
    }

// ---------------------------------------------------------------------------
// General MFMA 1x1-conv, 64n x 64co, BK=64. XBF16 selects bf16 X input.
// ---------------------------------------------------------------------------
template<bool RELU, bool XBF16>
__global__ __launch_bounds__(256) void conv_mfma(
    const float* __restrict__ W, long wbs,
    const void* __restrict__ Xv, long xbs,
    float* __restrict__ Y,
    const float* __restrict__ bias,
    const float* __restrict__ gamma_ptr,
    const float* __restrict__ resid, long rbs,
    int Co, int K, int N)
{
    const int b   = blockIdx.z;
    const int n0  = blockIdx.x * 64;
    const int co0 = blockIdx.y * 64;
    const float* Wb = W + (size_t)b * wbs;

    __shared__ __bf16 Xs[64][72];
    __shared__ __bf16 Ws[64][72];

    const int t    = threadIdx.x;
    const int w    = t >> 6;
    const int lane = t & 63;
    const int g    = lane >> 4;
    const int c    = lane & 15;

    f32x4 acc[4];
    #pragma unroll
    for (int cb = 0; cb < 4; ++cb) acc[cb] = (f32x4){0.f, 0.f, 0.f, 0.f};

    for (int kb = 0; kb < K; kb += 64) {
        if constexpr (XBF16) {
            STAGE_X64B(((const __bf16*)Xv + (size_t)b * xbs), kb)
        } else {
            STAGE_X64(((const float*)Xv + (size_t)b * xbs), kb)
        }
        {
            const int kh = (t & 3) * 16;
            const float* src = Wb + (size_t)(co0 + (t >> 2)) * K + kb + kh;
            STAGE_W64(src)
        }
        __syncthreads();
        CONV_MMA_STEP()
        __syncthreads();
    }

    const float gsc = gamma_ptr ? *gamma_ptr : 1.f;
    const int nb = n0 + 16 * w + 4 * g;
    #pragma unroll
    for (int cb = 0; cb < 4; ++cb) {
        int co = co0 + 16 * cb + c;
        float bv = bias ? bias[co] : 0.f;
        float4 o;
        float* op = &o.x;
        #pragma unroll
        for (int r = 0; r < 4; ++r) {
            float val = acc[cb][r] + bv;
            if (RELU) val = fmaxf(val, 0.f);
            val *= gsc;
            op[r] = val;
        }
        if (resid) {
            size_t roff = (size_t)b * rbs + (size_t)co * N + nb;
            float4 rv = *reinterpret_cast<const float4*>(&resid[roff]);
            o.x += rv.x; o.y += rv.y; o.z += rv.z; o.w += rv.w;
        }
        *reinterpret_cast<float4*>(&Y[(size_t)b * Co * N + (size_t)co * N + nb]) = o;
    }
}

// ---------------------------------------------------------------------------
// Dual conv (fp32 X): rows [0,128) = relu(Wlo@Xlo), [128,256) = relu(Whi@Xhi).
// OUTBF16 selects bf16 output. Grid (N/64, 4, B).
// ---------------------------------------------------------------------------
template<bool RELU, bool OUTBF16>
__global__ __launch_bounds__(256) void conv_dual(
    const float* __restrict__ Wlo, const float* __restrict__ Whi, int K,
    const float* __restrict__ Xlo, long xbslo,
    const float* __restrict__ Xhi, long xbshi,
    void* __restrict__ Y, long ybs, int N)
{
    const int b   = blockIdx.z;
    const int n0  = blockIdx.x * 64;
    const int co0 = blockIdx.y * 64;
    const bool lo = (co0 < 128);
    const float* Wb = lo ? (Wlo + (size_t)co0 * K) : (Whi + (size_t)(co0 - 128) * K);
    const float* Xb = lo ? (Xlo + (size_t)b * xbslo) : (Xhi + (size_t)b * xbshi);

    __shared__ __bf16 Xs[64][72];
    __shared__ __bf16 Ws[64][72];

    const int t    = threadIdx.x;
    const int w    = t >> 6;
    const int lane = t & 63;
    const int g    = lane >> 4;
    const int c    = lane & 15;

    f32x4 acc[4];
    #pragma unroll
    for (int cb = 0; cb < 4; ++cb) acc[cb] = (f32x4){0.f, 0.f, 0.f, 0.f};

    for (int kb = 0; kb < K; kb += 64) {
        STAGE_X64(Xb, kb)
        {
            const int kh = (t & 3) * 16;
            const float* src = Wb + (size_t)(t >> 2) * K + kb + kh;
            STAGE_W64(src)
        }
        __syncthreads();
        CONV_MMA_STEP()
        __syncthreads();
    }

    const int nb = n0 + 16 * w + 4 * g;
    #pragma unroll
    for (int cb = 0; cb < 4; ++cb) {
        int co = co0 + 16 * cb + c;
        if constexpr (OUTBF16) {
            bf16x4 o;
            #pragma unroll
            for (int r = 0; r < 4; ++r) {
                float val = acc[cb][r];
                if (RELU) val = fmaxf(val, 0.f);
                o[r] = (__bf16)val;
            }
            *reinterpret_cast<bf16x4*>(
                &((__bf16*)Y)[(size_t)b * ybs + (size_t)co * N + nb]) = o;
        } else {
            float4 o;
            float* op = &o.x;
            #pragma unroll
            for (int r = 0; r < 4; ++r) {
                float val = acc[cb][r];
                if (RELU) val = fmaxf(val, 0.f);
                op[r] = val;
            }
            *reinterpret_cast<float4*>(
                &((float*)Y)[(size_t)b * ybs + (size_t)co * N + nb]) = o;
        }
    }
}

// ---------------------------------------------------------------------------
// Concat-K conv, bf16 in / bf16 out: T = W1@X[0:128] + W2@X[128:256] + b1+b2.
// ---------------------------------------------------------------------------
__global__ __launch_bounds__(256) void conv_catk(
    const float* __restrict__ W1, const float* __restrict__ W2,
    const float* __restrict__ b1, const float* __restrict__ b2,
    const __bf16* __restrict__ X, long xbs,
    __bf16* __restrict__ Y, int N)
{
    const int b   = blockIdx.z;
    const int n0  = blockIdx.x * 64;
    const int co0 = blockIdx.y * 64;
    const __bf16* Xb = X + (size_t)b * xbs;

    __shared__ __bf16 Xs[64][72];
    __shared__ __bf16 Ws[64][72];

    const int t    = threadIdx.x;
    const int w    = t >> 6;
    const int lane = t & 63;
    const int g    = lane >> 4;
    const int c    = lane & 15;

    f32x4 acc[4];
    #pragma unroll
    for (int cb = 0; cb < 4; ++cb) acc[cb] = (f32x4){0.f, 0.f, 0.f, 0.f};

    for (int kb = 0; kb < 256; kb += 64) {
        STAGE_X64B(Xb, kb)
        {
            const int kh = (t & 3) * 16;
            const int kcol = kb + kh;
            const float* src = (kb < 128)
                ? (W1 + (size_t)(co0 + (t >> 2)) * 128 + kcol)
                : (W2 + (size_t)(co0 + (t >> 2)) * 128 + kcol - 128);
            STAGE_W64(src)
        }
        __syncthreads();
        CONV_MMA_STEP()
        __syncthreads();
    }

    const int nb = n0 + 16 * w + 4 * g;
    #pragma unroll
    for (int cb = 0; cb < 4; ++cb) {
        int co = co0 + 16 * cb + c;
        float bv = b1[co] + b2[co];
        bf16x4 o;
        #pragma unroll
        for (int r = 0; r < 4; ++r) o[r] = (__bf16)(acc[cb][r] + bv);
        *reinterpret_cast<bf16x4*>(&Y[(size_t)b * 256 * N + (size_t)co * N + nb]) = o;
    }
}

// ---------------------------------------------------------------------------
// Fused q/k/v conv from f1 (= F rows 0-127, batch stride 256N). 64-co, BK=64.
// ---------------------------------------------------------------------------
__global__ __launch_bounds__(256) void conv_qkv(
    const float* __restrict__ Wq, const float* __restrict__ bq,
    const float* __restrict__ Wk, const float* __restrict__ bk,
    const float* __restrict__ Wv, const float* __restrict__ bv,
    const float* __restrict__ F, __bf16* __restrict__ qkT,
    __bf16* __restrict__ Vbuf, int N)
{
    const int b   = blockIdx.z;
    const int n0  = blockIdx.x * 64;
    const int co0 = blockIdx.y * 64;
    const float* Xb = F + (size_t)b * 256 * N;   // f1 rows 0-127

    __shared__ __bf16 Xs[64][72];
    __shared__ __bf16 Ws[64][72];

    const int t    = threadIdx.x;
    const int w    = t >> 6;
    const int lane = t & 63;
    const int g    = lane >> 4;
    const int c    = lane & 15;

    f32x4 acc[4];
    #pragma unroll
    for (int cb = 0; cb < 4; ++cb) acc[cb] = (f32x4){0.f, 0.f, 0.f, 0.f};

    for (int kb = 0; kb < CI; kb += 64) {
        STAGE_X64(Xb, kb)
        {
            const int co = co0 + (t >> 2);
            const int kh = (t & 3) * 16;
            const float* src = (co < 32) ? (Wq + (size_t)co * CI)
                             : (co < 64) ? (Wk + (size_t)(co - 32) * CI)
                                         : (Wv + (size_t)(co - 64) * CI);
            src += kb + kh;
            STAGE_W64(src)
        }
        __syncthreads();
        CONV_MMA_STEP()
        __syncthreads();
    }

    const int nb = n0 + 16 * w + 4 * g;
    #pragma unroll
    for (int cb = 0; cb < 4; ++cb) {
        int co = co0 + 16 * cb + c;
        float bias = (co < 32) ? bq[co] : (co < 64) ? bk[co - 32] : bv[co - 64];
        if (co < 64) {
            #pragma unroll
            for (int r = 0; r < 4; ++r)
                qkT[((size_t)b * NN + nb + r) * 64 + co] = (__bf16)(acc[cb][r] + bias);
        } else {
            bf16x4 o;
            #pragma unroll
            for (int r = 0; r < 4; ++r) o[r] = (__bf16)(acc[cb][r] + bias);
            *reinterpret_cast<bf16x4*>(&Vbuf[((size_t)b * CI + co - 64) * NN + nb]) = o;
        }
    }
}

// ---------------------------------------------------------------------------
// PAM flash, NSPLIT=4 (R23 best config; 74 us).
// ---------------------------------------------------------------------------
__global__ __launch_bounds__(256) void pam_flash_mfma(
    const __bf16* __restrict__ qkT, const __bf16* __restrict__ Vbuf,
    Ptr4 op4,
    float* __restrict__ mp, float* __restrict__ lp, int N)
{
    const int b  = blockIdx.y;
    const int s  = blockIdx.z;
    const int n0 = blockIdx.x * 64;
    float* Op = op4.p[s];

    __shared__ __bf16 Vlds[2][128][40];
    __shared__ __bf16 QP[64][40];

    const int t    = threadIdx.x;
    const int w    = t >> 6;
    const int lane = t & 63;
    const int g    = lane >> 4;
    const int c    = lane & 15;

    bf16x8 qa = *reinterpret_cast<const bf16x8*>(
        &qkT[((size_t)b * NN + n0 + 16*w + c) * 64 + g * 8]);

    f32x4 acc[8];
    #pragma unroll
    for (int vbk = 0; vbk < 8; ++vbk) acc[vbk] = (f32x4){0.f, 0.f, 0.f, 0.f};
    float ms = -1e30f, ls = 0.f;

    const int mstart = s * KVLEN;
    const int NT = KVLEN / 32;

    auto stageV = [&](int mt, int buf) {
        const int cv  = t >> 1;
        const int sw  = (cv >> 3) & 3;
        const int ch0 = (t & 1) * 2;
        const __bf16* src = &Vbuf[((size_t)b * CI + cv) * NN + mstart + mt * 32 + ch0 * 8];
        *reinterpret_cast<bf16x8*>(&Vlds[buf][cv][((ch0 ^ sw) & 3) * 8]) =
            *reinterpret_cast<const bf16x8*>(src);
        *reinterpret_cast<bf16x8*>(&Vlds[buf][cv][(((ch0 + 1) ^ sw) & 3) * 8]) =
            *reinterpret_cast<const bf16x8*>(src + 8);
    };

    stageV(0, 0);
    __syncthreads();

    for (int mt = 0; mt < NT; ++mt) {
        const int buf = mt & 1;
        const int m0  = mstart + mt * 32;
        if (mt + 1 < NT) stageV(mt + 1, buf ^ 1);

        f32x4 sv[2];
        #pragma unroll
        for (int mb = 0; mb < 2; ++mb) {
            bf16x8 kf = *reinterpret_cast<const bf16x8*>(
                &qkT[((size_t)b * NN + m0 + 16*mb + c) * 64 + 32 + g * 8]);
            sv[mb] = __builtin_amdgcn_mfma_f32_16x16x32_bf16(
                kf, qa, (f32x4){0.f, 0.f, 0.f, 0.f}, 0, 0, 0);
        }

        float mx = sv[0][0];
        #pragma unroll
        for (int r = 1; r < 4; ++r) mx = fmaxf(mx, sv[0][r]);
        #pragma unroll
        for (int r = 0; r < 4; ++r) mx = fmaxf(mx, sv[1][r]);
        mx = fmaxf(mx, __shfl_xor(mx, 16));
        mx = fmaxf(mx, __shfl_xor(mx, 32));
        float mnew = fmaxf(ms, mx);
        float scale = __expf(ms - mnew);
        ms = mnew;
        float psum = 0.f;
        #pragma unroll
        for (int mb = 0; mb < 2; ++mb)
            #pragma unroll
            for (int r = 0; r < 4; ++r) {
                float p = __expf(sv[mb][r] - mnew);
                sv[mb][r] = p;
                psum += p;
            }
        psum += __shfl_xor(psum, 16);
        psum += __shfl_xor(psum, 32);
        ls = ls * scale + psum;

        #pragma unroll
        for (int mb = 0; mb < 2; ++mb) {
            bf16x4 pk;
            #pragma unroll
            for (int r = 0; r < 4; ++r) pk[r] = (__bf16)sv[mb][r];
            *reinterpret_cast<bf16x4*>(&QP[16*w + c][16*mb + 4*g]) = pk;
        }

        if (__any(scale != 1.0f)) {
            float sc[4];
            #pragma unroll
            for (int r = 0; r < 4; ++r) sc[r] = __shfl(scale, 4*g + r, 64);
            #pragma unroll
            for (int vbk = 0; vbk < 8; ++vbk)
                #pragma unroll
                for (int r = 0; r < 4; ++r) acc[vbk][r] *= sc[r];
        }

        bf16x8 pa = *reinterpret_cast<const bf16x8*>(&QP[16*w + c][g * 8]);
        #pragma unroll
        for (int vbk = 0; vbk < 8; ++vbk) {
            const int row = 16*vbk + c;
            const int sw  = (2*vbk + (c >> 3)) & 3;
            bf16x8 vf = *reinterpret_cast<const bf16x8*>(
                &Vlds[buf][row][((g ^ sw) & 3) * 8]);
            acc[vbk] = __builtin_amdgcn_mfma_f32_16x16x32_bf16(pa, vf, acc[vbk], 0, 0, 0);
        }
        __syncthreads();
    }

    #pragma unroll
    for (int vbk = 0; vbk < 8; ++vbk) {
        float4 o = { acc[vbk][0], acc[vbk][1], acc[vbk][2], acc[vbk][3] };
        *reinterpret_cast<float4*>(
            &Op[((size_t)(b * CI + 16*vbk + c)) * N + n0 + 16*w + 4*g]) = o;
    }
    if (g == 0) {
        int n = n0 + 16*w + c;
        mp[(size_t)(s * B + b) * N + n] = ms;
        lp[(size_t)(s * B + b) * N + n] = ls;
    }
}

// ---------------------------------------------------------------------------
// Merge NSPLIT=4 partials; writes sa IN-PLACE into f1 (F rows 0-127).
// ---------------------------------------------------------------------------
__global__ __launch_bounds__(256) void pam_merge(
    Ptr4 op4,
    const float* __restrict__ mp, const float* __restrict__ lp,
    float* __restrict__ F, const float* __restrict__ gamma_ptr)
{
    size_t idx = (size_t)blockIdx.x * 256 + threadIdx.x;
    const int n = (int)(idx & (NN - 1));
    const int b = (int)(idx >> 19);

    float m[NSPLIT], l[NSPLIT];
    float M = -1e30f;
    #pragma unroll
    for (int s = 0; s < NSPLIT; ++s) {
        m[s] = mp[(size_t)(s * B + b) * NN + n];
        l[s] = lp[(size_t)(s * B + b) * NN + n];
        M = fmaxf(M, m[s]);
    }
    float L = 0.f, O = 0.f;
    #pragma unroll
    for (int s = 0; s < NSPLIT; ++s) {
        float ws = __expf(m[s] - M);
        L += l[s] * ws;
        O += op4.p[s][idx] * ws;
    }
    size_t foff = (size_t)b * (256 * (size_t)NN) + (idx & ((1u << 19) - 1));
    F[foff] = (*gamma_ptr) * (O / L) + F[foff];
}

// ---------------------------------------------------------------------------
// CAM energy, K-split partials (strided f2 input).
// ---------------------------------------------------------------------------
__global__ __launch_bounds__(256) void cam_energy_part(
    const float* __restrict__ f2, long f2bs, float* __restrict__ ep, int N)
{
    const int b = blockIdx.x;
    const int s = blockIdx.y;
    const float* fb = f2 + (size_t)b * f2bs;
    const int kbase = s * (NN / ESPLIT);

    __shared__ float fs[128][33];
    const int t  = threadIdx.x;
    const int ti = t >> 4;
    const int tj = t & 15;

    float acc[8][8] = {};
    for (int st = 0; st < (NN / ESPLIT) / 32; ++st) {
        const int k0 = kbase + st * 32;
        {
            const int ch  = t >> 1;
            const int k16 = (t & 1) * 16;
            const float* src = fb + (size_t)ch * N + k0 + k16;
            #pragma unroll
            for (int j = 0; j < 4; ++j)
                *reinterpret_cast<float4*>(&fs[ch][k16 + 4*j]) =
                    *reinterpret_cast<const float4*>(src + 4*j);
        }
        __syncthreads();
        #pragma unroll 4
        for (int k = 0; k < 32; ++k) {
            float av[8], bv[8];
            #pragma unroll
            for (int ii = 0; ii < 8; ++ii) av[ii] = fs[ti * 8 + ii][k];
            #pragma unroll
            for (int jj = 0; jj < 8; ++jj) bv[jj] = fs[tj * 8 + jj][k];
            #pragma unroll
            for (int ii = 0; ii < 8; ++ii)
                #pragma unroll
                for (int jj = 0; jj < 8; ++jj)
                    acc[ii][jj] += av[ii] * bv[jj];
        }
        __syncthreads();
    }
    float* dst = ep + ((size_t)(s * B + b)) * CI * CI;
    #pragma unroll
    for (int ii = 0; ii < 8; ++ii)
        #pragma unroll
        for (int jj = 0; jj < 8; ++jj)
            dst[(size_t)(ti * 8 + ii) * CI + tj * 8 + jj] = acc[ii][jj];
}

__global__ __launch_bounds__(256) void cam_energy_reduce(
    const float* __restrict__ ep, float* __restrict__ came)
{
    const size_t n = (size_t)B * CI * CI;
    size_t idx = (size_t)blockIdx.x * 256 + threadIdx.x;
    float s = 0.f;
    #pragma unroll
    for (int j = 0; j < ESPLIT; ++j) s += ep[j * n + idx];
    came[idx] = s;
}

// ---------------------------------------------------------------------------
// CAM softmax: softmax(rowmax - e) == exp(rowmin - e)/sum.
// ---------------------------------------------------------------------------
__global__ __launch_bounds__(64) void cam_softmax(
    const float* __restrict__ e, float* __restrict__ attn)
{
    const int row = blockIdx.x;
    const float* er = e + (size_t)row * CI;
    const int t = threadIdx.x;
    float v0 = er[t], v1 = er[t + 64];
    float mn = fminf(v0, v1);
    #pragma unroll
    for (int off = 32; off; off >>= 1) mn = fminf(mn, __shfl_xor(mn, off));
    float p0 = __expf(mn - v0), p1 = __expf(mn - v1);
    float s = p0 + p1;
    #pragma unroll
    for (int off = 32; off; off >>= 1) s += __shfl_xor(s, off);
    float inv = 1.f / s;
    attn[(size_t)row * CI + t]      = p0 * inv;
    attn[(size_t)row * CI + t + 64] = p1 * inv;
}

// ---------------------------------------------------------------------------
extern "C" void kernel_launch(void* const* d_in, const int* in_sizes, int n_in,
                              void* d_out, int out_size, void* d_ws, size_t ws_size,
                              hipStream_t stream)
{
    const float* x    = (const float*)d_in[0];
    const float* Wa   = (const float*)d_in[1];
    const float* Wc   = (const float*)d_in[2];
    const float* Wq   = (const float*)d_in[3];
    const float* bq   = (const float*)d_in[4];
    const float* Wk   = (const float*)d_in[5];
    const float* bk   = (const float*)d_in[6];
    const float* Wv   = (const float*)d_in[7];
    const float* bv   = (const float*)d_in[8];
    const float* gpam = (const float*)d_in[9];
    const float* gcam = (const float*)d_in[10];
    const float* Wa1  = (const float*)d_in[11];
    const float* Wc1  = (const float*)d_in[12];
    const float* W1   = (const float*)d_in[13];
    const float* b1   = (const float*)d_in[14];
    const float* W2   = (const float*)d_in[15];
    const float* b2   = (const float*)d_in[16];
    const float* W3   = (const float*)d_in[17];
    const float* b3   = (const float*)d_in[18];
    float* out = (float*)d_out;

    // workspace layout (fp32 units) — ~63 MB
    const size_t PART = (size_t)B * CI * NN;   // 2,097,152
    float* ws    = (float*)d_ws;
    float*  F     = ws;                          // [B,256,N] fp32 (f1|f2), 2*PART
    float*  R2    = ws + 2 * PART;               // PART: epart early, S2 bf16 late
    float*  epart = R2;
    __bf16* S2bf  = (__bf16*)R2;
    float*  Csc   = ws + 3 * PART;               // [B,128,N] fp32
    __bf16* Tbf   = (__bf16*)(ws + 4 * PART);    // [B,256,N] bf16 = PART f32-eq
    float*  Opart = ws + 5 * PART;               // 2*PART: flash partials 0,1
    float*  mpart = ws + 7 * PART;               // [4][B][N] 65,536
    float*  lpart = mpart + 65536;
    float*  came  = lpart + 65536;
    float*  cama  = came + 65536;
    __bf16* qkT   = (__bf16*)(cama + 65536);         // [B][N][64] bf16
    __bf16* Vbuf  = (__bf16*)(cama + 65536 + 524288);// [B][128][N] bf16

    Ptr4 op4;
    op4.p[0] = Opart;  op4.p[1] = Opart + PART;
    op4.p[2] = out;    op4.p[3] = out + PART;    // d_out overwritten by W3 at end

    const dim3 blk(256);

    // 1. F = relu([Wa;Wc] @ x), fp32 out
    conv_dual<true, false><<<dim3(NN / 64, 4, B), blk, 0, stream>>>(
        Wa, Wc, CIN, x, (long)CIN * NN, x, (long)CIN * NN, F, (long)256 * NN, NN);
    // 2. qkT + Vbuf from f1
    conv_qkv<<<dim3(NN / 64, 3, B), blk, 0, stream>>>(
        Wq, bq, Wk, bk, Wv, bv, F, qkT, Vbuf, NN);
    // 3. flash partials
    pam_flash_mfma<<<dim3(NN / 64, B, NSPLIT), blk, 0, stream>>>(
        qkT, Vbuf, op4, mpart, lpart, NN);
    // 4. merge -> sa in-place into F rows 0-127
    pam_merge<<<dim3((B * CI * NN) / 256), blk, 0, stream>>>(
        op4, mpart, lpart, F, gpam);
    // 5. CAM energy (f2 = F rows 128+), partials into epart
    cam_energy_part<<<dim3(B, ESPLIT), blk, 0, stream>>>(
        F + (size_t)128 * NN, (long)256 * NN, epart, NN);
    cam_energy_reduce<<<dim3((B * CI * CI) / 256), blk, 0, stream>>>(epart, came);
    cam_softmax<<<dim3(B * CI), dim3(64), 0, stream>>>(came, cama);
    // 6. sc = gamma_cam * (attn @ f2) + f2 -> Csc (fp32)
    conv_mfma<false, false><<<dim3(NN / 64, 2, B), blk, 0, stream>>>(
        cama, (long)CI * CI, F + (size_t)128 * NN, (long)256 * NN, Csc,
        nullptr, gcam, F + (size_t)128 * NN, (long)256 * NN, CI, CI, NN);
    // 7. S2 = [relu(Wa1@sa) ; relu(Wc1@sc)] -> bf16 (epart dead now)
    conv_dual<true, true><<<dim3(NN / 64, 4, B), blk, 0, stream>>>(
        Wa1, Wc1, CI, F, (long)256 * NN, Csc, (long)CI * NN, S2bf, (long)256 * NN, NN);
    // 8. T = [W1 W2] @ S2 + b1 + b2 -> bf16
    conv_catk<<<dim3(NN / 64, 4, B), blk, 0, stream>>>(
        W1, W2, b1, b2, S2bf, (long)256 * NN, Tbf, NN);
    // 9. out = W3 @ T + b3 (bf16 X)
    conv_mfma<false, true><<<dim3(NN / 64, 4, B), blk, 0, stream>>>(
        W3, 0, Tbf, (long)COUT * NN, out, b3, nullptr, nullptr, 0, COUT, COUT, NN);
}